// Round 14
// baseline (155.829 us; speedup 1.0000x reference)
//
#include <hip/hip_runtime.h>
#include <hip/hip_bf16.h>
#include <hip/hip_fp8.h>
#include <stdint.h>

// Problem: N=4096 rows, D=768 dims.
//   dist[i][j] = ||A_i - P_j||;  scores = 50 - dist;  loss = mean_i(-log_softmax(scores)_ii)
// Fixed-shift softmax (scores <= 50 always): loss_i = dist_ii + log(sum_j exp(-dist_ij))
// R14 = R13 with the cvt_norms double-row-offset bug fixed (d4 is already
// row-based; index must be relative to the row start).
// Structure: fp8 GEMM, 256x128 block (4 waves, wave tile 128x64 -> 42.7 MACs/
// staged-byte), BK=64 (dbuf 48 KB -> 2 blocks/CU, all 512 blocks co-resident).
// 64B LDS rows with ADD-swizzle slot=(chunk+(row>>1))&3 (exact 2-way = free);
// cvt stores granule order [0,4,1,5,2,6,3,7] per 64B block so each lane-quad's
// two k-steps are one contiguous b128 (both halves used).

#define N_ROWS 4096
#define D_DIM  768
#define NITER (D_DIM / 64)               // 12 (BK=64 fp8 bytes)

typedef float f32x4 __attribute__((ext_vector_type(4)));
typedef int   i32x4 __attribute__((ext_vector_type(4)));

// ---------------- kernel 1: fp32 -> fp8 e4m3 cast (k-permuted) + norms + zero S --
// Within each 64B block (16 words): granule gw = w>>1 -> gp = ((gw&3)<<1)|(gw>>2).
__global__ __launch_bounds__(256) void cvt_norms(
        const float* __restrict__ A, const float* __restrict__ P,
        uint8_t* __restrict__ A8, uint8_t* __restrict__ P8,
        float* __restrict__ a2, float* __restrict__ p2, float* __restrict__ S) {
    const int t = threadIdx.x, lane = t & 63, wave = t >> 6;
    const int row = blockIdx.x * 4 + wave;
    const float* src = blockIdx.y ? P : A;
    uint8_t* dst = blockIdx.y ? P8 : A8;
    float* nrm = blockIdx.y ? p2 : a2;

    const float4* s4 = (const float4*)src + (size_t)row * (D_DIM / 4);
    uint32_t* d4 = (uint32_t*)dst + (size_t)row * (D_DIM / 4);   // row base
    float s = 0.0f;
#pragma unroll
    for (int c = 0; c < 3; c++) {
        const int wf = c * 64 + lane;            // word index in row (0..191)
        float4 v = s4[wf];
        s += v.x * v.x + v.y * v.y + v.z * v.z + v.w * v.w;
        union { uint32_t u; uint8_t b[4]; } pk;
        pk.b[0] = __hip_fp8_e4m3(v.x).__x;
        pk.b[1] = __hip_fp8_e4m3(v.y).__x;
        pk.b[2] = __hip_fp8_e4m3(v.z).__x;
        pk.b[3] = __hip_fp8_e4m3(v.w).__x;
        const int kb = wf >> 4, w16 = wf & 15;
        const int gw = w16 >> 1, h = w16 & 1;
        const int gp = ((gw & 3) << 1) | (gw >> 2);     // [0,4,1,5,2,6,3,7] order
        d4[(kb << 4) + (gp << 1) + h] = pk.u;           // FIX: relative to row base
    }
    for (int off = 32; off; off >>= 1) s += __shfl_down(s, off);
    if (lane == 0) {
        nrm[row] = s;
        if (blockIdx.y == 0) S[row] = 0.0f;
    }
}

// ---------------- kernel 2: double-buffered fp8 MFMA GEMM + softmax epilogue -----
__device__ __forceinline__ void g2l16(const void* g, void* l) {
    __builtin_amdgcn_global_load_lds(
        (const __attribute__((address_space(1))) void*)g,
        (__attribute__((address_space(3))) void*)l, 16, 0, 0);
}

__global__ __launch_bounds__(256) void gemm_fused(
        const uint8_t* __restrict__ A8, const uint8_t* __restrict__ P8,
        const float* __restrict__ a2, const float* __restrict__ p2,
        float* __restrict__ S, float* __restrict__ Dd) {
    __shared__ __align__(16) uint8_t As[2][256 * 64];   // 2 x 16 KB
    __shared__ __align__(16) uint8_t Bs[2][128 * 64];   // 2 x 8 KB

    // 1D grid, bm-major: consecutive bids share bm -> each XCD keeps one A-panel
    // (192 KB) + the whole B (3 MB) in its 4 MiB L2.
    const int bid = blockIdx.x;
    const int bm = bid >> 5, bn = bid & 31;

    const int t = threadIdx.x;
    const int lane = t & 63, wave = t >> 6;
    const int wm = wave >> 1, wn = wave & 1;   // wave tile: rows wm*128, cols wn*64

    f32x4 acc[8][4];
#pragma unroll
    for (int i = 0; i < 8; i++)
#pragma unroll
        for (int j = 0; j < 4; j++) acc[i][j] = (f32x4){0.f, 0.f, 0.f, 0.f};

    // staging: physical 16B chunk p = c*256+t -> LDS row r = p>>2 = c*64 + (t>>2),
    // slot s = t&3. Stored global chunk g satisfies s = (g + (r>>1))&3
    //   -> g = ((t&3) - (t>>3)) & 3   (c-invariant: c*32 % 4 == 0).
    const int gT = ((t & 3) - (t >> 3)) & 3;
    const size_t aBase = (size_t)(bm * 256 + (t >> 2)) * D_DIM + (size_t)gT * 16;
    const size_t bBase = (size_t)(bn * 128 + (t >> 2)) * D_DIM + (size_t)gT * 16;

    // LDS->frag read offsets (bytes). Row stride 64 B. Lane quad fq reads stored
    // chunk fq of its row at slot (fq + (R>>1))&3; b128 low 8B = k-step0 granule fq,
    // high 8B = k-step1 granule fq (cvt's granule interleave).
    const int fr = lane & 15, fq = lane >> 4;
    int aOff[8], bOff[4];
#pragma unroll
    for (int mi = 0; mi < 8; mi++) {
        const int R = wm * 128 + mi * 16 + fr;
        aOff[mi] = R * 64 + ((fq + (R >> 1)) & 3) * 16;
    }
#pragma unroll
    for (int ni = 0; ni < 4; ni++) {
        const int R = wn * 64 + ni * 16 + fr;
        bOff[ni] = R * 64 + ((fq + (R >> 1)) & 3) * 16;
    }

#define STAGE(K2, SEL)                                                            \
    do {                                                                          \
        const int k0_ = (K2) * 64;                                                \
        _Pragma("unroll")                                                         \
        for (int c = 0; c < 4; c++)                                               \
            g2l16(A8 + aBase + (size_t)c * (64 * D_DIM) + k0_,                    \
                  &As[SEL][(c * 256 + t) * 16]);                                  \
        _Pragma("unroll")                                                         \
        for (int c = 0; c < 2; c++)                                               \
            g2l16(P8 + bBase + (size_t)c * (64 * D_DIM) + k0_,                    \
                  &Bs[SEL][(c * 256 + t) * 16]);                                  \
    } while (0)

    STAGE(0, 0);

    for (int k = 0; k < NITER; k++) {
        const int cur = k & 1;
        // Only tile k's 6 loads outstanding, issued one full compute phase ago.
        asm volatile("s_waitcnt vmcnt(0)" ::: "memory");
        asm volatile("s_barrier" ::: "memory");
        if (k + 1 < NITER) STAGE(k + 1, cur ^ 1);   // fly during compute below

        i32x4 av[8], bv[4];
#pragma unroll
        for (int mi = 0; mi < 8; mi++)
            av[mi] = *(const i32x4*)&As[cur][aOff[mi]];
#pragma unroll
        for (int ni = 0; ni < 4; ni++)
            bv[ni] = *(const i32x4*)&Bs[cur][bOff[ni]];
#pragma unroll
        for (int step = 0; step < 2; step++) {
#pragma unroll
            for (int mi = 0; mi < 8; mi++) {
                const long long afh = ((const long long*)&av[mi])[step];
#pragma unroll
                for (int ni = 0; ni < 4; ni++) {
                    const long long bfh = ((const long long*)&bv[ni])[step];
                    acc[mi][ni] = __builtin_amdgcn_mfma_f32_16x16x32_fp8_fp8(
                        afh, bfh, acc[mi][ni], 0, 0, 0);
                }
            }
        }
    }
#undef STAGE

    // ---- epilogue: dist -> exp(-dist), per-row partial sums, diagonal capture ----
    // C/D layout (16x16, shape-determined): col = lane&15, row = (lane>>4)*4 + reg
    float p2v[4];
#pragma unroll
    for (int ni = 0; ni < 4; ni++)
        p2v[ni] = p2[bn * 128 + wn * 64 + ni * 16 + fr];
    const int colBase = bn * 128 + wn * 64 + fr;

#pragma unroll
    for (int mi = 0; mi < 8; mi++) {
#pragma unroll
        for (int r = 0; r < 4; r++) {
            const int gi = bm * 256 + wm * 128 + mi * 16 + fq * 4 + r;
            const float a2v = a2[gi];
            float rs = 0.0f;
#pragma unroll
            for (int ni = 0; ni < 4; ni++) {
                const float cross = acc[mi][ni][r];
                const float sq = a2v + p2v[ni] - 2.0f * cross;
                const float dist = sqrtf(fmaxf(sq, 0.0f) + 1e-12f);
                const int gj = colBase + ni * 16;
                if (gi == gj) Dd[gi] = dist;
                rs += __expf(-dist);
            }
            rs += __shfl_xor(rs, 1);
            rs += __shfl_xor(rs, 2);
            rs += __shfl_xor(rs, 4);
            rs += __shfl_xor(rs, 8);
            if (fr == 0) atomicAdd(&S[gi], rs);
        }
    }
}

// ---------------- kernel 3: final reduce -> scalar -------------------------------
__global__ void finalize(const float* __restrict__ S, const float* __restrict__ Dd,
                         float* __restrict__ out) {
    const int t = threadIdx.x;
    float s = 0.0f;
    for (int i = t; i < N_ROWS; i += 256) s += Dd[i] + logf(S[i]);
    for (int off = 32; off; off >>= 1) s += __shfl_down(s, off);
    __shared__ float wsum[4];
    if ((t & 63) == 0) wsum[t >> 6] = s;
    __syncthreads();
    if (t == 0) out[0] = (wsum[0] + wsum[1] + wsum[2] + wsum[3]) * (1.0f / N_ROWS);
}

// ---------------- fallback (undersized workspace): naive fp32 --------------------
__global__ void zero_out1(float* __restrict__ out) {
    if (threadIdx.x == 0 && blockIdx.x == 0) out[0] = 0.0f;
}
__global__ void naive_row(const float* __restrict__ A, const float* __restrict__ P,
                          float* __restrict__ out) {
    __shared__ float arow[D_DIM];
    const int i = blockIdx.x, t = threadIdx.x;
    for (int c = t; c < D_DIM; c += 256) arow[c] = A[(size_t)i * D_DIM + c];
    __syncthreads();
    float sumexp = 0.0f, ddiag = 0.0f;
    for (int j = t; j < N_ROWS; j += 256) {
        const float* p = P + (size_t)j * D_DIM;
        float d2 = 0.0f;
        for (int c = 0; c < D_DIM; c++) { float df = arow[c] - p[c]; d2 += df * df; }
        float dist = sqrtf(fmaxf(d2, 0.0f) + 1e-12f);
        if (j == i) ddiag = dist;
        sumexp += __expf(-dist);
    }
    for (int off = 32; off; off >>= 1) {
        sumexp += __shfl_down(sumexp, off);
        ddiag  += __shfl_down(ddiag, off);
    }
    __shared__ float w1[4], w2[4];
    if ((t & 63) == 0) { w1[t >> 6] = sumexp; w2[t >> 6] = ddiag; }
    __syncthreads();
    if (t == 0) {
        float se = w1[0] + w1[1] + w1[2] + w1[3];
        float dd = w2[0] + w2[1] + w2[2] + w2[3];
        atomicAdd(out, (dd + logf(se)) * (1.0f / N_ROWS));
    }
}

extern "C" void kernel_launch(void* const* d_in, const int* in_sizes, int n_in,
                              void* d_out, int out_size, void* d_ws, size_t ws_size,
                              hipStream_t stream) {
    const float* A = (const float*)d_in[0];
    const float* P = (const float*)d_in[1];
    float* out = (float*)d_out;

    const size_t F8_BYTES = (size_t)N_ROWS * D_DIM;          // 3145728 per matrix
    const size_t V_BYTES  = (size_t)N_ROWS * sizeof(float);  // 16384
    const size_t NEED = 2 * F8_BYTES + 4 * V_BYTES;

    if (ws_size >= NEED) {
        char* ws = (char*)d_ws;
        uint8_t* A8 = (uint8_t*)(ws);
        uint8_t* P8 = (uint8_t*)(ws + F8_BYTES);
        float* a2 = (float*)(ws + 2 * F8_BYTES);
        float* p2 = (float*)(ws + 2 * F8_BYTES + V_BYTES);
        float* S  = (float*)(ws + 2 * F8_BYTES + 2 * V_BYTES);
        float* Dd = (float*)(ws + 2 * F8_BYTES + 3 * V_BYTES);

        hipLaunchKernelGGL(cvt_norms, dim3(N_ROWS / 4, 2), dim3(256), 0, stream,
                           A, P, A8, P8, a2, p2, S);
        hipLaunchKernelGGL(gemm_fused, dim3((N_ROWS / 256) * (N_ROWS / 128)), dim3(256),
                           0, stream, A8, P8, a2, p2, S, Dd);
        hipLaunchKernelGGL(finalize, dim3(1), dim3(256), 0, stream, S, Dd, out);
    } else {
        hipLaunchKernelGGL(zero_out1, dim3(1), dim3(64), 0, stream, out);
        hipLaunchKernelGGL(naive_row, dim3(N_ROWS), dim3(256), 0, stream, A, P, out);
    }
}

// Round 15
// 114.712 us; speedup vs baseline: 1.3584x; 1.3584x over previous
//
#include <hip/hip_runtime.h>
#include <hip/hip_bf16.h>
#include <hip/hip_fp8.h>
#include <stdint.h>

// Problem: N=4096 rows, D=768 dims.
//   dist[i][j] = ||A_i - P_j||;  scores = 50 - dist;  loss = mean_i(-log_softmax(scores)_ii)
// Fixed-shift softmax (scores <= 50 always): loss_i = dist_ii + log(sum_j exp(-dist_ij))
// R15 = R12's block structure (128x128, 4 waves, 64x64 wave tiles, acc 64 VGPR ->
// 3 waves/SIMD) + R14's PROVEN conflict-free 64B-row LDS geometry (ADD-swizzle
// slot=(chunk+(row>>1))&3, granule order [0,4,1,5,2,6,3,7] -> pure b128 frags,
// measured 0 conflicts) + BK=64 (dbuf 32 KB -> 3 blocks/CU co-resident, flipping
// the per-CU iter balance to compute-dominant: 857 cyc staging vs 1536 cyc MFMA).

#define N_ROWS 4096
#define D_DIM  768
#define GRID_DIM (N_ROWS / 128)          // 32
#define NITER (D_DIM / 64)               // 12 (BK=64 fp8 bytes)

typedef float f32x4 __attribute__((ext_vector_type(4)));
typedef int   i32x4 __attribute__((ext_vector_type(4)));

// ---------------- kernel 1: fp32 -> fp8 e4m3 cast (k-permuted) + norms + zero S --
// Within each 64B block (16 words): granule gw = w>>1 -> gp = ((gw&3)<<1)|(gw>>2).
__global__ __launch_bounds__(256) void cvt_norms(
        const float* __restrict__ A, const float* __restrict__ P,
        uint8_t* __restrict__ A8, uint8_t* __restrict__ P8,
        float* __restrict__ a2, float* __restrict__ p2, float* __restrict__ S) {
    const int t = threadIdx.x, lane = t & 63, wave = t >> 6;
    const int row = blockIdx.x * 4 + wave;
    const float* src = blockIdx.y ? P : A;
    uint8_t* dst = blockIdx.y ? P8 : A8;
    float* nrm = blockIdx.y ? p2 : a2;

    const float4* s4 = (const float4*)src + (size_t)row * (D_DIM / 4);
    uint32_t* d4 = (uint32_t*)dst + (size_t)row * (D_DIM / 4);   // row base
    float s = 0.0f;
#pragma unroll
    for (int c = 0; c < 3; c++) {
        const int wf = c * 64 + lane;            // word index in row (0..191)
        float4 v = s4[wf];
        s += v.x * v.x + v.y * v.y + v.z * v.z + v.w * v.w;
        union { uint32_t u; uint8_t b[4]; } pk;
        pk.b[0] = __hip_fp8_e4m3(v.x).__x;
        pk.b[1] = __hip_fp8_e4m3(v.y).__x;
        pk.b[2] = __hip_fp8_e4m3(v.z).__x;
        pk.b[3] = __hip_fp8_e4m3(v.w).__x;
        const int kb = wf >> 4, w16 = wf & 15;
        const int gw = w16 >> 1, h = w16 & 1;
        const int gp = ((gw & 3) << 1) | (gw >> 2);     // [0,4,1,5,2,6,3,7] order
        d4[(kb << 4) + (gp << 1) + h] = pk.u;           // relative to row base
    }
    for (int off = 32; off; off >>= 1) s += __shfl_down(s, off);
    if (lane == 0) {
        nrm[row] = s;
        if (blockIdx.y == 0) S[row] = 0.0f;
    }
}

// ---------------- kernel 2: double-buffered fp8 MFMA GEMM + softmax epilogue -----
__device__ __forceinline__ void g2l16(const void* g, void* l) {
    __builtin_amdgcn_global_load_lds(
        (const __attribute__((address_space(1))) void*)g,
        (__attribute__((address_space(3))) void*)l, 16, 0, 0);
}

__global__ __launch_bounds__(256) void gemm_fused(
        const uint8_t* __restrict__ A8, const uint8_t* __restrict__ P8,
        const float* __restrict__ a2, const float* __restrict__ p2,
        float* __restrict__ S, float* __restrict__ Dd) {
    __shared__ __align__(16) uint8_t As[2][128 * 64];   // 2 x 8 KB
    __shared__ __align__(16) uint8_t Bs[2][128 * 64];   // 2 x 8 KB

    const int bm = blockIdx.x, bn = blockIdx.y;
    const int t = threadIdx.x;
    const int lane = t & 63, wave = t >> 6;
    const int wm = wave >> 1, wn = wave & 1;   // 2x2 waves, 64x64 tiles

    f32x4 acc[4][4];
#pragma unroll
    for (int i = 0; i < 4; i++)
#pragma unroll
        for (int j = 0; j < 4; j++) acc[i][j] = (f32x4){0.f, 0.f, 0.f, 0.f};

    // staging: physical 16B chunk p = c*256+t -> LDS row r = p>>2 = c*64 + (t>>2),
    // slot s = t&3. Stored global chunk g: s = (g + (r>>1))&3
    //   -> g = ((t&3) - (t>>3)) & 3   (c-invariant: c*32 % 4 == 0).
    const int gT = ((t & 3) - (t >> 3)) & 3;
    const size_t aBase = (size_t)(bm * 128 + (t >> 2)) * D_DIM + (size_t)gT * 16;
    const size_t bBase = (size_t)(bn * 128 + (t >> 2)) * D_DIM + (size_t)gT * 16;

    // LDS->frag read offsets (bytes). Row stride 64 B. Lane quad fq reads stored
    // chunk fq of its row at slot (fq + (R>>1))&3; b128 low 8B = k-step0 granule,
    // high 8B = k-step1 granule (cvt's interleave). Measured 0 conflicts (R14).
    const int fr = lane & 15, fq = lane >> 4;
    int aOff[4], bOff[4];
#pragma unroll
    for (int mi = 0; mi < 4; mi++) {
        const int R = wm * 64 + mi * 16 + fr;
        aOff[mi] = R * 64 + ((fq + (R >> 1)) & 3) * 16;
    }
#pragma unroll
    for (int ni = 0; ni < 4; ni++) {
        const int R = wn * 64 + ni * 16 + fr;
        bOff[ni] = R * 64 + ((fq + (R >> 1)) & 3) * 16;
    }

#define STAGE(K2, SEL)                                                            \
    do {                                                                          \
        const int k0_ = (K2) * 64;                                                \
        _Pragma("unroll")                                                         \
        for (int c = 0; c < 2; c++)                                               \
            g2l16(A8 + aBase + (size_t)c * (64 * D_DIM) + k0_,                    \
                  &As[SEL][(c * 256 + t) * 16]);                                  \
        _Pragma("unroll")                                                         \
        for (int c = 0; c < 2; c++)                                               \
            g2l16(P8 + bBase + (size_t)c * (64 * D_DIM) + k0_,                    \
                  &Bs[SEL][(c * 256 + t) * 16]);                                  \
    } while (0)

    STAGE(0, 0);

    for (int k = 0; k < NITER; k++) {
        const int cur = k & 1;
        // Only tile k's 4 loads outstanding, issued one full compute phase ago.
        asm volatile("s_waitcnt vmcnt(0)" ::: "memory");
        asm volatile("s_barrier" ::: "memory");
        if (k + 1 < NITER) STAGE(k + 1, cur ^ 1);   // fly during compute below

        i32x4 av[4], bv[4];
#pragma unroll
        for (int mi = 0; mi < 4; mi++)
            av[mi] = *(const i32x4*)&As[cur][aOff[mi]];
#pragma unroll
        for (int ni = 0; ni < 4; ni++)
            bv[ni] = *(const i32x4*)&Bs[cur][bOff[ni]];
#pragma unroll
        for (int step = 0; step < 2; step++) {
#pragma unroll
            for (int mi = 0; mi < 4; mi++) {
                const long long afh = ((const long long*)&av[mi])[step];
#pragma unroll
                for (int ni = 0; ni < 4; ni++) {
                    const long long bfh = ((const long long*)&bv[ni])[step];
                    acc[mi][ni] = __builtin_amdgcn_mfma_f32_16x16x32_fp8_fp8(
                        afh, bfh, acc[mi][ni], 0, 0, 0);
                }
            }
        }
    }
#undef STAGE

    // ---- epilogue: dist -> exp(-dist), per-row partial sums, diagonal capture ----
    // C/D layout (16x16, shape-determined): col = lane&15, row = (lane>>4)*4 + reg
    float p2v[4];
#pragma unroll
    for (int ni = 0; ni < 4; ni++)
        p2v[ni] = p2[bn * 128 + wn * 64 + ni * 16 + fr];
    const int colBase = bn * 128 + wn * 64 + fr;

#pragma unroll
    for (int mi = 0; mi < 4; mi++) {
#pragma unroll
        for (int r = 0; r < 4; r++) {
            const int gi = bm * 128 + wm * 64 + mi * 16 + fq * 4 + r;
            const float a2v = a2[gi];
            float rs = 0.0f;
#pragma unroll
            for (int ni = 0; ni < 4; ni++) {
                const float cross = acc[mi][ni][r];
                const float sq = a2v + p2v[ni] - 2.0f * cross;
                const float dist = sqrtf(fmaxf(sq, 0.0f) + 1e-12f);
                const int gj = colBase + ni * 16;
                if (gi == gj) Dd[gi] = dist;
                rs += __expf(-dist);
            }
            rs += __shfl_xor(rs, 1);
            rs += __shfl_xor(rs, 2);
            rs += __shfl_xor(rs, 4);
            rs += __shfl_xor(rs, 8);
            if (fr == 0) atomicAdd(&S[gi], rs);
        }
    }
}

// ---------------- kernel 3: final reduce -> scalar -------------------------------
__global__ void finalize(const float* __restrict__ S, const float* __restrict__ Dd,
                         float* __restrict__ out) {
    const int t = threadIdx.x;
    float s = 0.0f;
    for (int i = t; i < N_ROWS; i += 256) s += Dd[i] + logf(S[i]);
    for (int off = 32; off; off >>= 1) s += __shfl_down(s, off);
    __shared__ float wsum[4];
    if ((t & 63) == 0) wsum[t >> 6] = s;
    __syncthreads();
    if (t == 0) out[0] = (wsum[0] + wsum[1] + wsum[2] + wsum[3]) * (1.0f / N_ROWS);
}

// ---------------- fallback (undersized workspace): naive fp32 --------------------
__global__ void zero_out1(float* __restrict__ out) {
    if (threadIdx.x == 0 && blockIdx.x == 0) out[0] = 0.0f;
}
__global__ void naive_row(const float* __restrict__ A, const float* __restrict__ P,
                          float* __restrict__ out) {
    __shared__ float arow[D_DIM];
    const int i = blockIdx.x, t = threadIdx.x;
    for (int c = t; c < D_DIM; c += 256) arow[c] = A[(size_t)i * D_DIM + c];
    __syncthreads();
    float sumexp = 0.0f, ddiag = 0.0f;
    for (int j = t; j < N_ROWS; j += 256) {
        const float* p = P + (size_t)j * D_DIM;
        float d2 = 0.0f;
        for (int c = 0; c < D_DIM; c++) { float df = arow[c] - p[c]; d2 += df * df; }
        float dist = sqrtf(fmaxf(d2, 0.0f) + 1e-12f);
        if (j == i) ddiag = dist;
        sumexp += __expf(-dist);
    }
    for (int off = 32; off; off >>= 1) {
        sumexp += __shfl_down(sumexp, off);
        ddiag  += __shfl_down(ddiag, off);
    }
    __shared__ float w1[4], w2[4];
    if ((t & 63) == 0) { w1[t >> 6] = sumexp; w2[t >> 6] = ddiag; }
    __syncthreads();
    if (t == 0) {
        float se = w1[0] + w1[1] + w1[2] + w1[3];
        float dd = w2[0] + w2[1] + w2[2] + w2[3];
        atomicAdd(out, (dd + logf(se)) * (1.0f / N_ROWS));
    }
}

extern "C" void kernel_launch(void* const* d_in, const int* in_sizes, int n_in,
                              void* d_out, int out_size, void* d_ws, size_t ws_size,
                              hipStream_t stream) {
    const float* A = (const float*)d_in[0];
    const float* P = (const float*)d_in[1];
    float* out = (float*)d_out;

    const size_t F8_BYTES = (size_t)N_ROWS * D_DIM;          // 3145728 per matrix
    const size_t V_BYTES  = (size_t)N_ROWS * sizeof(float);  // 16384
    const size_t NEED = 2 * F8_BYTES + 4 * V_BYTES;

    if (ws_size >= NEED) {
        char* ws = (char*)d_ws;
        uint8_t* A8 = (uint8_t*)(ws);
        uint8_t* P8 = (uint8_t*)(ws + F8_BYTES);
        float* a2 = (float*)(ws + 2 * F8_BYTES);
        float* p2 = (float*)(ws + 2 * F8_BYTES + V_BYTES);
        float* S  = (float*)(ws + 2 * F8_BYTES + 2 * V_BYTES);
        float* Dd = (float*)(ws + 2 * F8_BYTES + 3 * V_BYTES);

        hipLaunchKernelGGL(cvt_norms, dim3(N_ROWS / 4, 2), dim3(256), 0, stream,
                           A, P, A8, P8, a2, p2, S);
        hipLaunchKernelGGL(gemm_fused, dim3(GRID_DIM, GRID_DIM), dim3(256), 0, stream,
                           A8, P8, a2, p2, S, Dd);
        hipLaunchKernelGGL(finalize, dim3(1), dim3(256), 0, stream, S, Dd, out);
    } else {
        hipLaunchKernelGGL(zero_out1, dim3(1), dim3(64), 0, stream, out);
        hipLaunchKernelGGL(naive_row, dim3(N_ROWS), dim3(256), 0, stream, A, P, out);
    }
}

// Round 16
// 114.286 us; speedup vs baseline: 1.3635x; 1.0037x over previous
//
#include <hip/hip_runtime.h>
#include <hip/hip_bf16.h>
#include <hip/hip_fp8.h>
#include <stdint.h>

// Problem: N=4096 rows, D=768 dims.
//   dist[i][j] = ||A_i - P_j||;  scores = 50 - dist;  loss = mean_i(-log_softmax(scores)_ii)
// Fixed-shift softmax (scores <= 50 always): loss_i = dist_ii + log(sum_j exp(-dist_ij))
// R16 = R15 (fp8, 128x128 block, 64x64 wave tiles, conflict-free 64B-row LDS:
// ADD-swizzle slot=(chunk+(row>>1))&3 + granule order [0,4,1,5,2,6,3,7] -> pure
// b128 frags, measured 0 conflicts) with a TRIPLE-buffered K-loop: tile k's loads
// are issued at iter k-2 (2-iteration lead ~9000 cyc >> L2 latency+service), the
// per-iter wait is vmcnt(4) (drain tile k only; k+1's loads stay in flight).

#define N_ROWS 4096
#define D_DIM  768
#define GRID_DIM (N_ROWS / 128)          // 32
#define NITER (D_DIM / 64)               // 12 (BK=64 fp8 bytes)
#define BUFB  (128 * 64)                 // 8 KB per buffer per matrix

typedef float f32x4 __attribute__((ext_vector_type(4)));
typedef int   i32x4 __attribute__((ext_vector_type(4)));

// ---------------- kernel 1: fp32 -> fp8 e4m3 cast (k-permuted) + norms + zero S --
// Within each 64B block (16 words): granule gw = w>>1 -> gp = ((gw&3)<<1)|(gw>>2).
__global__ __launch_bounds__(256) void cvt_norms(
        const float* __restrict__ A, const float* __restrict__ P,
        uint8_t* __restrict__ A8, uint8_t* __restrict__ P8,
        float* __restrict__ a2, float* __restrict__ p2, float* __restrict__ S) {
    const int t = threadIdx.x, lane = t & 63, wave = t >> 6;
    const int row = blockIdx.x * 4 + wave;
    const float* src = blockIdx.y ? P : A;
    uint8_t* dst = blockIdx.y ? P8 : A8;
    float* nrm = blockIdx.y ? p2 : a2;

    const float4* s4 = (const float4*)src + (size_t)row * (D_DIM / 4);
    uint32_t* d4 = (uint32_t*)dst + (size_t)row * (D_DIM / 4);   // row base
    float s = 0.0f;
#pragma unroll
    for (int c = 0; c < 3; c++) {
        const int wf = c * 64 + lane;            // word index in row (0..191)
        float4 v = s4[wf];
        s += v.x * v.x + v.y * v.y + v.z * v.z + v.w * v.w;
        union { uint32_t u; uint8_t b[4]; } pk;
        pk.b[0] = __hip_fp8_e4m3(v.x).__x;
        pk.b[1] = __hip_fp8_e4m3(v.y).__x;
        pk.b[2] = __hip_fp8_e4m3(v.z).__x;
        pk.b[3] = __hip_fp8_e4m3(v.w).__x;
        const int kb = wf >> 4, w16 = wf & 15;
        const int gw = w16 >> 1, h = w16 & 1;
        const int gp = ((gw & 3) << 1) | (gw >> 2);     // [0,4,1,5,2,6,3,7] order
        d4[(kb << 4) + (gp << 1) + h] = pk.u;           // relative to row base
    }
    for (int off = 32; off; off >>= 1) s += __shfl_down(s, off);
    if (lane == 0) {
        nrm[row] = s;
        if (blockIdx.y == 0) S[row] = 0.0f;
    }
}

// ---------------- kernel 2: triple-buffered fp8 MFMA GEMM + softmax epilogue -----
__device__ __forceinline__ void g2l16(const void* g, void* l) {
    __builtin_amdgcn_global_load_lds(
        (const __attribute__((address_space(1))) void*)g,
        (__attribute__((address_space(3))) void*)l, 16, 0, 0);
}

__global__ __launch_bounds__(256) void gemm_fused(
        const uint8_t* __restrict__ A8, const uint8_t* __restrict__ P8,
        const float* __restrict__ a2, const float* __restrict__ p2,
        float* __restrict__ S, float* __restrict__ Dd) {
    __shared__ __align__(16) uint8_t As[3 * BUFB];   // 3 x 8 KB
    __shared__ __align__(16) uint8_t Bs[3 * BUFB];   // 3 x 8 KB

    const int bm = blockIdx.x, bn = blockIdx.y;
    const int t = threadIdx.x;
    const int lane = t & 63, wave = t >> 6;
    const int wm = wave >> 1, wn = wave & 1;   // 2x2 waves, 64x64 tiles

    f32x4 acc[4][4];
#pragma unroll
    for (int i = 0; i < 4; i++)
#pragma unroll
        for (int j = 0; j < 4; j++) acc[i][j] = (f32x4){0.f, 0.f, 0.f, 0.f};

    // staging: physical 16B chunk p = c*256+t -> LDS row r = c*64 + (t>>2),
    // slot s = t&3. Stored global chunk g: s = (g + (r>>1))&3
    //   -> g = ((t&3) - (t>>3)) & 3   (c-invariant: c*32 % 4 == 0).
    const int gT = ((t & 3) - (t >> 3)) & 3;
    const size_t aBase = (size_t)(bm * 128 + (t >> 2)) * D_DIM + (size_t)gT * 16;
    const size_t bBase = (size_t)(bn * 128 + (t >> 2)) * D_DIM + (size_t)gT * 16;

    // LDS->frag read offsets (bytes). Row stride 64 B. Lane quad fq reads stored
    // chunk fq of its row at slot (fq + (R>>1))&3; b128 low 8B = k-step0 granule,
    // high 8B = k-step1 granule. Measured 0 conflicts (R14/R15).
    const int fr = lane & 15, fq = lane >> 4;
    int aOff[4], bOff[4];
#pragma unroll
    for (int mi = 0; mi < 4; mi++) {
        const int R = wm * 64 + mi * 16 + fr;
        aOff[mi] = R * 64 + ((fq + (R >> 1)) & 3) * 16;
    }
#pragma unroll
    for (int ni = 0; ni < 4; ni++) {
        const int R = wn * 64 + ni * 16 + fr;
        bOff[ni] = R * 64 + ((fq + (R >> 1)) & 3) * 16;
    }

#define STAGE(K2, SEL)                                                            \
    do {                                                                          \
        const int k0_ = (K2) * 64;                                                \
        const int lb_ = (SEL) * BUFB;                                             \
        _Pragma("unroll")                                                         \
        for (int c = 0; c < 2; c++)                                               \
            g2l16(A8 + aBase + (size_t)c * (64 * D_DIM) + k0_,                    \
                  &As[lb_ + (c * 256 + t) * 16]);                                 \
        _Pragma("unroll")                                                         \
        for (int c = 0; c < 2; c++)                                               \
            g2l16(P8 + bBase + (size_t)c * (64 * D_DIM) + k0_,                    \
                  &Bs[lb_ + (c * 256 + t) * 16]);                                 \
    } while (0)

    STAGE(0, 0);
    STAGE(1, 1);

    int s0 = 0;                                  // buffer holding tile k
    for (int k = 0; k < NITER; k++) {
        // Drain tile k's 4 loads (issued at iter k-2, ~2 iterations of lead);
        // tile k+1's 4 loads stay in flight across the barrier.
        if (k == NITER - 1) asm volatile("s_waitcnt vmcnt(0)" ::: "memory");
        else                asm volatile("s_waitcnt vmcnt(4)" ::: "memory");
        asm volatile("s_barrier" ::: "memory");
        if (k + 2 < NITER) {
            int s2 = s0 + 2; if (s2 >= 3) s2 -= 3;
            STAGE(k + 2, s2);                    // WAR-safe: buf read in iter k-1
        }

        const int lb = s0 * BUFB;
        i32x4 av[4], bv[4];
#pragma unroll
        for (int mi = 0; mi < 4; mi++)
            av[mi] = *(const i32x4*)&As[lb + aOff[mi]];
#pragma unroll
        for (int ni = 0; ni < 4; ni++)
            bv[ni] = *(const i32x4*)&Bs[lb + bOff[ni]];
#pragma unroll
        for (int step = 0; step < 2; step++) {
#pragma unroll
            for (int mi = 0; mi < 4; mi++) {
                const long long afh = ((const long long*)&av[mi])[step];
#pragma unroll
                for (int ni = 0; ni < 4; ni++) {
                    const long long bfh = ((const long long*)&bv[ni])[step];
                    acc[mi][ni] = __builtin_amdgcn_mfma_f32_16x16x32_fp8_fp8(
                        afh, bfh, acc[mi][ni], 0, 0, 0);
                }
            }
        }
        s0 = (s0 == 2) ? 0 : s0 + 1;
    }
#undef STAGE

    // ---- epilogue: dist -> exp(-dist), per-row partial sums, diagonal capture ----
    // C/D layout (16x16, shape-determined): col = lane&15, row = (lane>>4)*4 + reg
    float p2v[4];
#pragma unroll
    for (int ni = 0; ni < 4; ni++)
        p2v[ni] = p2[bn * 128 + wn * 64 + ni * 16 + fr];
    const int colBase = bn * 128 + wn * 64 + fr;

#pragma unroll
    for (int mi = 0; mi < 4; mi++) {
#pragma unroll
        for (int r = 0; r < 4; r++) {
            const int gi = bm * 128 + wm * 64 + mi * 16 + fq * 4 + r;
            const float a2v = a2[gi];
            float rs = 0.0f;
#pragma unroll
            for (int ni = 0; ni < 4; ni++) {
                const float cross = acc[mi][ni][r];
                const float sq = a2v + p2v[ni] - 2.0f * cross;
                const float dist = sqrtf(fmaxf(sq, 0.0f) + 1e-12f);
                const int gj = colBase + ni * 16;
                if (gi == gj) Dd[gi] = dist;
                rs += __expf(-dist);
            }
            rs += __shfl_xor(rs, 1);
            rs += __shfl_xor(rs, 2);
            rs += __shfl_xor(rs, 4);
            rs += __shfl_xor(rs, 8);
            if (fr == 0) atomicAdd(&S[gi], rs);
        }
    }
}

// ---------------- kernel 3: final reduce -> scalar -------------------------------
__global__ void finalize(const float* __restrict__ S, const float* __restrict__ Dd,
                         float* __restrict__ out) {
    const int t = threadIdx.x;
    float s = 0.0f;
    for (int i = t; i < N_ROWS; i += 256) s += Dd[i] + logf(S[i]);
    for (int off = 32; off; off >>= 1) s += __shfl_down(s, off);
    __shared__ float wsum[4];
    if ((t & 63) == 0) wsum[t >> 6] = s;
    __syncthreads();
    if (t == 0) out[0] = (wsum[0] + wsum[1] + wsum[2] + wsum[3]) * (1.0f / N_ROWS);
}

// ---------------- fallback (undersized workspace): naive fp32 --------------------
__global__ void zero_out1(float* __restrict__ out) {
    if (threadIdx.x == 0 && blockIdx.x == 0) out[0] = 0.0f;
}
__global__ void naive_row(const float* __restrict__ A, const float* __restrict__ P,
                          float* __restrict__ out) {
    __shared__ float arow[D_DIM];
    const int i = blockIdx.x, t = threadIdx.x;
    for (int c = t; c < D_DIM; c += 256) arow[c] = A[(size_t)i * D_DIM + c];
    __syncthreads();
    float sumexp = 0.0f, ddiag = 0.0f;
    for (int j = t; j < N_ROWS; j += 256) {
        const float* p = P + (size_t)j * D_DIM;
        float d2 = 0.0f;
        for (int c = 0; c < D_DIM; c++) { float df = arow[c] - p[c]; d2 += df * df; }
        float dist = sqrtf(fmaxf(d2, 0.0f) + 1e-12f);
        if (j == i) ddiag = dist;
        sumexp += __expf(-dist);
    }
    for (int off = 32; off; off >>= 1) {
        sumexp += __shfl_down(sumexp, off);
        ddiag  += __shfl_down(ddiag, off);
    }
    __shared__ float w1[4], w2[4];
    if ((t & 63) == 0) { w1[t >> 6] = sumexp; w2[t >> 6] = ddiag; }
    __syncthreads();
    if (t == 0) {
        float se = w1[0] + w1[1] + w1[2] + w1[3];
        float dd = w2[0] + w2[1] + w2[2] + w2[3];
        atomicAdd(out, (dd + logf(se)) * (1.0f / N_ROWS));
    }
}

extern "C" void kernel_launch(void* const* d_in, const int* in_sizes, int n_in,
                              void* d_out, int out_size, void* d_ws, size_t ws_size,
                              hipStream_t stream) {
    const float* A = (const float*)d_in[0];
    const float* P = (const float*)d_in[1];
    float* out = (float*)d_out;

    const size_t F8_BYTES = (size_t)N_ROWS * D_DIM;          // 3145728 per matrix
    const size_t V_BYTES  = (size_t)N_ROWS * sizeof(float);  // 16384
    const size_t NEED = 2 * F8_BYTES + 4 * V_BYTES;

    if (ws_size >= NEED) {
        char* ws = (char*)d_ws;
        uint8_t* A8 = (uint8_t*)(ws);
        uint8_t* P8 = (uint8_t*)(ws + F8_BYTES);
        float* a2 = (float*)(ws + 2 * F8_BYTES);
        float* p2 = (float*)(ws + 2 * F8_BYTES + V_BYTES);
        float* S  = (float*)(ws + 2 * F8_BYTES + 2 * V_BYTES);
        float* Dd = (float*)(ws + 2 * F8_BYTES + 3 * V_BYTES);

        hipLaunchKernelGGL(cvt_norms, dim3(N_ROWS / 4, 2), dim3(256), 0, stream,
                           A, P, A8, P8, a2, p2, S);
        hipLaunchKernelGGL(gemm_fused, dim3(GRID_DIM, GRID_DIM), dim3(256), 0, stream,
                           A8, P8, a2, p2, S, Dd);
        hipLaunchKernelGGL(finalize, dim3(1), dim3(256), 0, stream, S, Dd, out);
    } else {
        hipLaunchKernelGGL(zero_out1, dim3(1), dim3(64), 0, stream, out);
        hipLaunchKernelGGL(naive_row, dim3(N_ROWS), dim3(256), 0, stream, A, P, out);
    }
}